// Round 1
// baseline (904.111 us; speedup 1.0000x reference)
//
#include <hip/hip_runtime.h>

#define NN 50000
#define NE 800000
#define DIN 64
#define HD 128

// ---------------- CSR construction ----------------

__global__ void count_edges(const int* __restrict__ dst, int* __restrict__ cnt) {
    int e = blockIdx.x * blockDim.x + threadIdx.x;
    if (e < NE) atomicAdd(&cnt[dst[e]], 1);
}

__global__ void scan_counts(const int* __restrict__ cnt, int* __restrict__ rowptr,
                            float* __restrict__ invcnt) {
    __shared__ int part[1024];
    int tid = threadIdx.x;
    const int CH = (NN + 1023) / 1024;  // 49
    int base = tid * CH;
    int s = 0;
    for (int i = 0; i < CH; ++i) { int idx = base + i; if (idx < NN) s += cnt[idx]; }
    part[tid] = s;
    __syncthreads();
    for (int off = 1; off < 1024; off <<= 1) {
        int add = (tid >= off) ? part[tid - off] : 0;
        __syncthreads();
        part[tid] += add;
        __syncthreads();
    }
    int excl = (tid == 0) ? 0 : part[tid - 1];
    for (int i = 0; i < CH; ++i) {
        int idx = base + i;
        if (idx < NN) {
            rowptr[idx] = excl;
            int c = cnt[idx];
            invcnt[idx] = 1.0f / (float)(c > 0 ? c : 1);
            excl += c;
        }
    }
    if (tid == 1023) rowptr[NN] = part[1023];
}

__global__ void scatter_edges(const int* __restrict__ src, const int* __restrict__ dst,
                              const int* __restrict__ rowptr, int* __restrict__ fill,
                              int* __restrict__ csr_src) {
    int e = blockIdx.x * blockDim.x + threadIdx.x;
    if (e >= NE) return;
    int d = dst[e];
    int pos = rowptr[d] + atomicAdd(&fill[d], 1);
    csr_src[pos] = src[e];
}

// ---------------- weight transpose (once per call) ----------------

__global__ void transpose_w(const float* __restrict__ W, float* __restrict__ WT, int D) {
    int i = blockIdx.x * blockDim.x + threadIdx.x;  // over HD*D elements, W is [HD][D]
    if (i >= HD * D) return;
    int c = i / D, k = i - c * D;
    WT[k * HD + c] = W[i];
}

// ---------------- mean aggregation (gather over CSR) ----------------

template <int D>
__global__ void gather_mean(const float* __restrict__ h, const int* __restrict__ rowptr,
                            const int* __restrict__ csr_src, const float* __restrict__ invcnt,
                            float* __restrict__ M) {
    int n = blockIdx.x;
    int c = threadIdx.x;  // D threads
    int beg = rowptr[n], end = rowptr[n + 1];
    float acc = 0.0f;
    for (int e = beg; e < end; ++e) {
        int s = csr_src[e];
        acc += h[(size_t)s * D + c];
    }
    M[(size_t)n * D + c] = acc * invcnt[n];
}

// ---------------- fused linear + bias + L2 norm + (ReLU) ----------------

template <int D, bool RELU>
__global__ void linear_norm(const float* __restrict__ M, const float* __restrict__ Hin,
                            const float* __restrict__ WlT, const float* __restrict__ bias,
                            const float* __restrict__ WrT, float* __restrict__ out) {
    __shared__ float ms[D];
    __shared__ float hs[D];
    __shared__ float red[2];
    int n = blockIdx.x;
    int c = threadIdx.x;  // HD = 128 threads
    if (c < D) {
        ms[c] = M[(size_t)n * D + c];
        hs[c] = Hin[(size_t)n * D + c];
    }
    __syncthreads();
    float acc = bias[c];
#pragma unroll 8
    for (int k = 0; k < D; ++k) {
        acc = fmaf(ms[k], WlT[k * HD + c], acc);
        acc = fmaf(hs[k], WrT[k * HD + c], acc);
    }
    float sq = acc * acc;
#pragma unroll
    for (int off = 1; off < 64; off <<= 1) sq += __shfl_xor(sq, off, 64);
    if ((c & 63) == 0) red[c >> 6] = sq;
    __syncthreads();
    float nrm = sqrtf(red[0] + red[1]);
    nrm = fmaxf(nrm, 1e-12f);
    float v = acc / nrm;
    if (RELU) v = fmaxf(v, 0.0f);
    out[(size_t)n * HD + c] = v;
}

// ---------------- launch ----------------

static inline size_t align256(size_t x) { return (x + 255) & ~(size_t)255; }

extern "C" void kernel_launch(void* const* d_in, const int* in_sizes, int n_in,
                              void* d_out, int out_size, void* d_ws, size_t ws_size,
                              hipStream_t stream) {
    const float* x   = (const float*)d_in[0];
    const int*   ei  = (const int*)d_in[1];
    const float* Wl0 = (const float*)d_in[2];
    const float* bl0 = (const float*)d_in[3];
    const float* Wr0 = (const float*)d_in[4];
    const float* Wl1 = (const float*)d_in[5];
    const float* bl1 = (const float*)d_in[6];
    const float* Wr1 = (const float*)d_in[7];
    const float* Wl2 = (const float*)d_in[8];
    const float* bl2 = (const float*)d_in[9];
    const float* Wr2 = (const float*)d_in[10];

    const int* src = ei;
    const int* dst = ei + NE;

    // workspace carve-up
    char* p = (char*)d_ws;
    size_t off = 0;
    int* fill = (int*)(p + off);        off = align256(off + (size_t)NN * 4);
    int* rowptr = (int*)(p + off);      off = align256(off + (size_t)(NN + 1) * 4);
    int* csr_src = (int*)(p + off);     off = align256(off + (size_t)NE * 4);
    float* invcnt = (float*)(p + off);  off = align256(off + (size_t)NN * 4);
    float* Hb = (float*)(p + off);      off = align256(off + (size_t)NN * HD * 4);
    float* Mb = (float*)(p + off);      off = align256(off + (size_t)NN * HD * 4);
    float* WlT0 = (float*)(p + off);    off = align256(off + (size_t)DIN * HD * 4);
    float* WrT0 = (float*)(p + off);    off = align256(off + (size_t)DIN * HD * 4);
    float* WlT1 = (float*)(p + off);    off = align256(off + (size_t)HD * HD * 4);
    float* WrT1 = (float*)(p + off);    off = align256(off + (size_t)HD * HD * 4);
    float* WlT2 = (float*)(p + off);    off = align256(off + (size_t)HD * HD * 4);
    float* WrT2 = (float*)(p + off);    off = align256(off + (size_t)HD * HD * 4);
    (void)ws_size; (void)n_in; (void)in_sizes; (void)out_size;

    float* out = (float*)d_out;

    const int EB = 256;
    const int EG = (NE + EB - 1) / EB;

    // CSR build (per call; deterministic counts, bucket order only affects fp sum order)
    hipMemsetAsync(fill, 0, (size_t)NN * 4, stream);
    count_edges<<<EG, EB, 0, stream>>>(dst, fill);
    scan_counts<<<1, 1024, 0, stream>>>(fill, rowptr, invcnt);
    hipMemsetAsync(fill, 0, (size_t)NN * 4, stream);
    scatter_edges<<<EG, EB, 0, stream>>>(src, dst, rowptr, fill, csr_src);

    // transpose weights
    transpose_w<<<(HD * DIN + 255) / 256, 256, 0, stream>>>(Wl0, WlT0, DIN);
    transpose_w<<<(HD * DIN + 255) / 256, 256, 0, stream>>>(Wr0, WrT0, DIN);
    transpose_w<<<(HD * HD + 255) / 256, 256, 0, stream>>>(Wl1, WlT1, HD);
    transpose_w<<<(HD * HD + 255) / 256, 256, 0, stream>>>(Wr1, WrT1, HD);
    transpose_w<<<(HD * HD + 255) / 256, 256, 0, stream>>>(Wl2, WlT2, HD);
    transpose_w<<<(HD * HD + 255) / 256, 256, 0, stream>>>(Wr2, WrT2, HD);

    // layer 0: x (64ch) -> Hb
    gather_mean<DIN><<<NN, DIN, 0, stream>>>(x, rowptr, csr_src, invcnt, Mb);
    linear_norm<DIN, true><<<NN, HD, 0, stream>>>(Mb, x, WlT0, bl0, WrT0, Hb);

    // layer 1: Hb -> Mb (in-place over mean is row-exclusive safe)
    gather_mean<HD><<<NN, HD, 0, stream>>>(Hb, rowptr, csr_src, invcnt, Mb);
    linear_norm<HD, true><<<NN, HD, 0, stream>>>(Mb, Hb, WlT1, bl1, WrT1, Mb);

    // layer 2: Mb -> d_out (mean into Hb, which is now free)
    gather_mean<HD><<<NN, HD, 0, stream>>>(Mb, rowptr, csr_src, invcnt, Hb);
    linear_norm<HD, false><<<NN, HD, 0, stream>>>(Hb, Mb, WlT2, bl2, WrT2, out);
}

// Round 2
// 533.623 us; speedup vs baseline: 1.6943x; 1.6943x over previous
//
#include <hip/hip_runtime.h>

#define NN 50000
#define NE 800000
#define DIN 64
#define HD 128

// ---------------- CSR construction ----------------

__global__ void count_edges(const int* __restrict__ dst, int* __restrict__ cnt) {
    int e = blockIdx.x * blockDim.x + threadIdx.x;
    if (e < NE) atomicAdd(&cnt[dst[e]], 1);
}

__global__ void scan_counts(const int* __restrict__ cnt, int* __restrict__ rowptr,
                            float* __restrict__ invcnt) {
    __shared__ int part[1024];
    int tid = threadIdx.x;
    const int CH = (NN + 1023) / 1024;  // 49
    int base = tid * CH;
    int s = 0;
    for (int i = 0; i < CH; ++i) { int idx = base + i; if (idx < NN) s += cnt[idx]; }
    part[tid] = s;
    __syncthreads();
    for (int off = 1; off < 1024; off <<= 1) {
        int add = (tid >= off) ? part[tid - off] : 0;
        __syncthreads();
        part[tid] += add;
        __syncthreads();
    }
    int excl = (tid == 0) ? 0 : part[tid - 1];
    for (int i = 0; i < CH; ++i) {
        int idx = base + i;
        if (idx < NN) {
            rowptr[idx] = excl;
            int c = cnt[idx];
            invcnt[idx] = 1.0f / (float)(c > 0 ? c : 1);
            excl += c;
        }
    }
    if (tid == 1023) rowptr[NN] = part[1023];
}

__global__ void scatter_edges(const int* __restrict__ src, const int* __restrict__ dst,
                              const int* __restrict__ rowptr, int* __restrict__ fill,
                              int* __restrict__ csr_src) {
    int e = blockIdx.x * blockDim.x + threadIdx.x;
    if (e >= NE) return;
    int d = dst[e];
    int pos = rowptr[d] + atomicAdd(&fill[d], 1);
    csr_src[pos] = src[e];
}

// ---------------- concat-transpose weights: WT[k][c] for k in [0,2D) ----------------

__global__ void build_wt(const float* __restrict__ Wl, const float* __restrict__ Wr,
                         float* __restrict__ WT, int D) {
    int i = blockIdx.x * blockDim.x + threadIdx.x;  // over 2D*HD
    if (i >= 2 * D * HD) return;
    int k = i / HD, c = i - (i / HD) * HD;
    WT[i] = (k < D) ? Wl[c * D + k] : Wr[c * D + (k - D)];
}

// ---------------- mean aggregation (gather over CSR, float4 + edge-parallel) ----------------

template <int D>
__global__ void gather_mean(const float* __restrict__ h, const int* __restrict__ rowptr,
                            const int* __restrict__ csr_src, const float* __restrict__ invcnt,
                            float* __restrict__ Mo) {
    constexpr int C4 = D / 4;      // float4 cols per row: 16 or 32
    constexpr int EG = 128 / C4;   // parallel edge groups: 8 or 4
    __shared__ float4 red[128];
    int n = blockIdx.x;
    int t = threadIdx.x;
    int c4 = t & (C4 - 1);
    int g = t / C4;
    int beg = rowptr[n], end = rowptr[n + 1];
    float4 acc = {0.f, 0.f, 0.f, 0.f};
    for (int e = beg + g; e < end; e += EG) {
        const float4* row = (const float4*)(h + (size_t)csr_src[e] * D);
        float4 v = row[c4];
        acc.x += v.x; acc.y += v.y; acc.z += v.z; acc.w += v.w;
    }
    red[t] = acc;
    __syncthreads();
    if (g == 0) {
#pragma unroll
        for (int j = 1; j < EG; ++j) {
            float4 v = red[j * C4 + c4];
            acc.x += v.x; acc.y += v.y; acc.z += v.z; acc.w += v.w;
        }
        float ic = invcnt[n];
        acc.x *= ic; acc.y *= ic; acc.z *= ic; acc.w *= ic;
        ((float4*)(Mo + (size_t)n * D))[c4] = acc;
    }
}

// ---------------- fused GEMM + bias + L2 norm + (ReLU) ----------------
// out[32 rows x 128 cols] per block; 256 threads; thread owns 4 rows x 4 cols.
// in_sT: transposed inputs in LDS, [k][r] with XOR swizzle on r (bits 2..4 by (k>>2)&7).
// Weights WT[k][c] read directly from global (L1/L2-resident, coalesced float4).

template <int D, bool RELU>
__global__ void linear_norm(const float* __restrict__ M, const float* __restrict__ H,
                            const float* __restrict__ WT, const float* __restrict__ bias,
                            float* __restrict__ out) {
    constexpr int K = 2 * D;
    constexpr int K4 = K / 4;
    __shared__ float in_sT[K * 32];

    int tid = threadIdx.x;
    int n0 = blockIdx.x * 32;

    // ---- stage inputs transposed (coalesced float4 reads, swizzled scatter writes) ----
    for (int idx = tid; idx < 32 * K4; idx += 256) {
        int r = idx / K4;
        int k4 = idx - r * K4;
        int k = k4 * 4;
        int row = n0 + r;
        float4 v = {0.f, 0.f, 0.f, 0.f};
        if (row < NN) {
            const float* src = (k < D) ? (M + (size_t)row * D + k)
                                       : (H + (size_t)row * D + (k - D));
            v = *(const float4*)src;
        }
        int rs = r ^ ((k4 & 7) << 2);
        in_sT[(k + 0) * 32 + rs] = v.x;
        in_sT[(k + 1) * 32 + rs] = v.y;
        in_sT[(k + 2) * 32 + rs] = v.z;
        in_sT[(k + 3) * 32 + rs] = v.w;
    }
    __syncthreads();

    int c0 = (tid & 31) * 4;       // output column group (covers 128 within 32 lanes)
    int r0 = (tid >> 5) * 4;       // row group (8 groups x 4 rows = 32 rows)

    float acc[4][4] = {};
#pragma unroll 8
    for (int k = 0; k < K; ++k) {
        float4 wv = *(const float4*)&WT[(size_t)k * HD + c0];
        int rs0 = r0 ^ (((k >> 2) & 7) << 2);
        float4 iv = *(const float4*)&in_sT[k * 32 + rs0];
        acc[0][0] = fmaf(iv.x, wv.x, acc[0][0]);
        acc[0][1] = fmaf(iv.x, wv.y, acc[0][1]);
        acc[0][2] = fmaf(iv.x, wv.z, acc[0][2]);
        acc[0][3] = fmaf(iv.x, wv.w, acc[0][3]);
        acc[1][0] = fmaf(iv.y, wv.x, acc[1][0]);
        acc[1][1] = fmaf(iv.y, wv.y, acc[1][1]);
        acc[1][2] = fmaf(iv.y, wv.z, acc[1][2]);
        acc[1][3] = fmaf(iv.y, wv.w, acc[1][3]);
        acc[2][0] = fmaf(iv.z, wv.x, acc[2][0]);
        acc[2][1] = fmaf(iv.z, wv.y, acc[2][1]);
        acc[2][2] = fmaf(iv.z, wv.z, acc[2][2]);
        acc[2][3] = fmaf(iv.z, wv.w, acc[2][3]);
        acc[3][0] = fmaf(iv.w, wv.x, acc[3][0]);
        acc[3][1] = fmaf(iv.w, wv.y, acc[3][1]);
        acc[3][2] = fmaf(iv.w, wv.z, acc[3][2]);
        acc[3][3] = fmaf(iv.w, wv.w, acc[3][3]);
    }

    // ---- epilogue: bias, row L2-norm (reduce across 32 col-lanes), relu, store ----
    float4 bv = *(const float4*)&bias[c0];
    float sq[4];
#pragma unroll
    for (int i = 0; i < 4; ++i) {
        acc[i][0] += bv.x; acc[i][1] += bv.y; acc[i][2] += bv.z; acc[i][3] += bv.w;
        sq[i] = acc[i][0] * acc[i][0] + acc[i][1] * acc[i][1] +
                acc[i][2] * acc[i][2] + acc[i][3] * acc[i][3];
    }
#pragma unroll
    for (int off = 1; off < 32; off <<= 1) {
#pragma unroll
        for (int i = 0; i < 4; ++i) sq[i] += __shfl_xor(sq[i], off, 64);
    }
#pragma unroll
    for (int i = 0; i < 4; ++i) {
        int row = n0 + r0 + i;
        if (row < NN) {
            float nrm = fmaxf(sqrtf(sq[i]), 1e-12f);
            float inv = 1.0f / nrm;
            float4 o;
            o.x = acc[i][0] * inv;
            o.y = acc[i][1] * inv;
            o.z = acc[i][2] * inv;
            o.w = acc[i][3] * inv;
            if (RELU) {
                o.x = fmaxf(o.x, 0.f); o.y = fmaxf(o.y, 0.f);
                o.z = fmaxf(o.z, 0.f); o.w = fmaxf(o.w, 0.f);
            }
            *(float4*)&out[(size_t)row * HD + c0] = o;
        }
    }
}

// ---------------- launch ----------------

static inline size_t align256(size_t x) { return (x + 255) & ~(size_t)255; }

extern "C" void kernel_launch(void* const* d_in, const int* in_sizes, int n_in,
                              void* d_out, int out_size, void* d_ws, size_t ws_size,
                              hipStream_t stream) {
    const float* x   = (const float*)d_in[0];
    const int*   ei  = (const int*)d_in[1];
    const float* Wl0 = (const float*)d_in[2];
    const float* bl0 = (const float*)d_in[3];
    const float* Wr0 = (const float*)d_in[4];
    const float* Wl1 = (const float*)d_in[5];
    const float* bl1 = (const float*)d_in[6];
    const float* Wr1 = (const float*)d_in[7];
    const float* Wl2 = (const float*)d_in[8];
    const float* bl2 = (const float*)d_in[9];
    const float* Wr2 = (const float*)d_in[10];

    const int* src = ei;
    const int* dst = ei + NE;

    // workspace carve-up
    char* p = (char*)d_ws;
    size_t off = 0;
    int* fill = (int*)(p + off);        off = align256(off + (size_t)NN * 4);
    int* rowptr = (int*)(p + off);      off = align256(off + (size_t)(NN + 1) * 4);
    int* csr_src = (int*)(p + off);     off = align256(off + (size_t)NE * 4);
    float* invcnt = (float*)(p + off);  off = align256(off + (size_t)NN * 4);
    float* Hb = (float*)(p + off);      off = align256(off + (size_t)NN * HD * 4);
    float* Mb = (float*)(p + off);      off = align256(off + (size_t)NN * HD * 4);
    float* WT0 = (float*)(p + off);     off = align256(off + (size_t)2 * DIN * HD * 4);
    float* WT1 = (float*)(p + off);     off = align256(off + (size_t)2 * HD * HD * 4);
    float* WT2 = (float*)(p + off);     off = align256(off + (size_t)2 * HD * HD * 4);
    (void)ws_size; (void)n_in; (void)in_sizes; (void)out_size;

    float* out = (float*)d_out;

    const int EB = 256;
    const int EG = (NE + EB - 1) / EB;

    // CSR build
    hipMemsetAsync(fill, 0, (size_t)NN * 4, stream);
    count_edges<<<EG, EB, 0, stream>>>(dst, fill);
    scan_counts<<<1, 1024, 0, stream>>>(fill, rowptr, invcnt);
    hipMemsetAsync(fill, 0, (size_t)NN * 4, stream);
    scatter_edges<<<EG, EB, 0, stream>>>(src, dst, rowptr, fill, csr_src);

    // concat-transposed weights
    build_wt<<<(2 * DIN * HD + 255) / 256, 256, 0, stream>>>(Wl0, Wr0, WT0, DIN);
    build_wt<<<(2 * HD * HD + 255) / 256, 256, 0, stream>>>(Wl1, Wr1, WT1, HD);
    build_wt<<<(2 * HD * HD + 255) / 256, 256, 0, stream>>>(Wl2, Wr2, WT2, HD);

    const int LG = (NN + 31) / 32;  // 1563

    // layer 0: x (64ch) -> Hb
    gather_mean<DIN><<<NN, 128, 0, stream>>>(x, rowptr, csr_src, invcnt, Mb);
    linear_norm<DIN, true><<<LG, 256, 0, stream>>>(Mb, x, WT0, bl0, Hb);

    // layer 1: Hb -> Mb (row-exclusive in-place safe: rows staged before written)
    gather_mean<HD><<<NN, 128, 0, stream>>>(Hb, rowptr, csr_src, invcnt, Mb);
    linear_norm<HD, true><<<LG, 256, 0, stream>>>(Mb, Hb, WT1, bl1, Mb);

    // layer 2: Mb -> d_out
    gather_mean<HD><<<NN, 128, 0, stream>>>(Mb, rowptr, csr_src, invcnt, Hb);
    linear_norm<HD, false><<<LG, 256, 0, stream>>>(Hb, Mb, WT2, bl2, out);
}

// Round 3
// 412.303 us; speedup vs baseline: 2.1928x; 1.2943x over previous
//
#include <hip/hip_runtime.h>

#define NN 50000
#define NE 800000
#define DIN 64
#define HD 128

// ---------------- CSR construction ----------------

__global__ void count_edges(const int* __restrict__ dst, int* __restrict__ cnt) {
    int e4 = blockIdx.x * blockDim.x + threadIdx.x;   // NE/4 = 200000 threads
    if (e4 * 4 >= NE) return;
    int4 d = ((const int4*)dst)[e4];
    atomicAdd(&cnt[d.x], 1);
    atomicAdd(&cnt[d.y], 1);
    atomicAdd(&cnt[d.z], 1);
    atomicAdd(&cnt[d.w], 1);
}

// hierarchical exclusive scan of cnt[NN] -> rowptr (3 kernels)

__global__ void partial_scan(const int* __restrict__ cnt, int* __restrict__ rowptr,
                             int* __restrict__ bsums) {
    __shared__ int sh[256];
    int t = threadIdx.x;
    int i = blockIdx.x * 256 + t;
    int v = (i < NN) ? cnt[i] : 0;
    sh[t] = v;
    __syncthreads();
#pragma unroll
    for (int off = 1; off < 256; off <<= 1) {
        int add = (t >= off) ? sh[t - off] : 0;
        __syncthreads();
        sh[t] += add;
        __syncthreads();
    }
    if (i < NN) rowptr[i] = sh[t] - v;          // block-local exclusive
    if (t == 255) bsums[blockIdx.x] = sh[255];  // block total
}

__global__ void scan_bsums(int* __restrict__ bsums, int nb) {
    __shared__ int sh[256];
    int t = threadIdx.x;
    int v = (t < nb) ? bsums[t] : 0;
    sh[t] = v;
    __syncthreads();
#pragma unroll
    for (int off = 1; off < 256; off <<= 1) {
        int add = (t >= off) ? sh[t - off] : 0;
        __syncthreads();
        sh[t] += add;
        __syncthreads();
    }
    if (t < nb) bsums[t] = sh[t] - v;  // exclusive
}

__global__ void finalize_scan(const int* __restrict__ cnt, int* __restrict__ rowptr,
                              const int* __restrict__ bsums, float* __restrict__ invcnt) {
    int i = blockIdx.x * 256 + threadIdx.x;
    if (i >= NN) return;
    int r = rowptr[i] + bsums[blockIdx.x];
    rowptr[i] = r;
    int c = cnt[i];
    invcnt[i] = 1.0f / (float)(c > 0 ? c : 1);
    if (i == NN - 1) rowptr[NN] = r + c;
}

__global__ void scatter_edges(const int* __restrict__ src, const int* __restrict__ dst,
                              const int* __restrict__ rowptr, int* __restrict__ fill,
                              int* __restrict__ csr_src) {
    int e = blockIdx.x * blockDim.x + threadIdx.x;
    if (e >= NE) return;
    int d = dst[e];
    int pos = rowptr[d] + atomicAdd(&fill[d], 1);
    csr_src[pos] = src[e];
}

// ---------------- concat-transpose weights (all 3 layers, one kernel) ----------------
// WT[k][c], k in [0,2D): rows of Wl then Wr, transposed to column-major-by-c.

__global__ void build_wt_all(const float* __restrict__ Wl0, const float* __restrict__ Wr0,
                             const float* __restrict__ Wl1, const float* __restrict__ Wr1,
                             const float* __restrict__ Wl2, const float* __restrict__ Wr2,
                             float* __restrict__ WT0, float* __restrict__ WT1,
                             float* __restrict__ WT2) {
    const int S0 = 2 * DIN * HD;          // 16384
    const int S12 = 2 * HD * HD;          // 32768
    int i = blockIdx.x * blockDim.x + threadIdx.x;
    if (i < S0) {
        int k = i / HD, c = i - k * HD;
        WT0[i] = (k < DIN) ? Wl0[c * DIN + k] : Wr0[c * DIN + (k - DIN)];
        return;
    }
    int j = i - S0;
    if (j < S12) {
        int k = j / HD, c = j - k * HD;
        WT1[j] = (k < HD) ? Wl1[c * HD + k] : Wr1[c * HD + (k - HD)];
        return;
    }
    int m = j - S12;
    if (m < S12) {
        int k = m / HD, c = m - k * HD;
        WT2[m] = (k < HD) ? Wl2[c * HD + k] : Wr2[c * HD + (k - HD)];
    }
}

// ---------------- mean aggregation (gather over CSR, float4 + edge-parallel) ----------------

template <int D>
__global__ void gather_mean(const float* __restrict__ h, const int* __restrict__ rowptr,
                            const int* __restrict__ csr_src, const float* __restrict__ invcnt,
                            float* __restrict__ Mo) {
    constexpr int C4 = D / 4;      // float4 cols per row: 16 or 32
    constexpr int EG = 128 / C4;   // parallel edge groups: 8 or 4
    __shared__ float4 red[128];
    int n = blockIdx.x;
    int t = threadIdx.x;
    int c4 = t & (C4 - 1);
    int g = t / C4;
    int beg = rowptr[n], end = rowptr[n + 1];
    float4 acc = {0.f, 0.f, 0.f, 0.f};
    for (int e = beg + g; e < end; e += EG) {
        const float4* row = (const float4*)(h + (size_t)csr_src[e] * D);
        float4 v = row[c4];
        acc.x += v.x; acc.y += v.y; acc.z += v.z; acc.w += v.w;
    }
    red[t] = acc;
    __syncthreads();
    if (g == 0) {
#pragma unroll
        for (int j = 1; j < EG; ++j) {
            float4 v = red[j * C4 + c4];
            acc.x += v.x; acc.y += v.y; acc.z += v.z; acc.w += v.w;
        }
        float ic = invcnt[n];
        acc.x *= ic; acc.y *= ic; acc.z *= ic; acc.w *= ic;
        ((float4*)(Mo + (size_t)n * D))[c4] = acc;
    }
}

// ---------------- fused GEMM + bias + L2 norm + (ReLU) ----------------
// out[32 rows x 128 cols] per block; 256 threads; thread owns 4 rows x 4 cols.

template <int D, bool RELU>
__global__ void linear_norm(const float* __restrict__ M, const float* __restrict__ H,
                            const float* __restrict__ WT, const float* __restrict__ bias,
                            float* __restrict__ out) {
    constexpr int K = 2 * D;
    constexpr int K4 = K / 4;
    __shared__ float in_sT[K * 32];

    int tid = threadIdx.x;
    int n0 = blockIdx.x * 32;

    // stage inputs transposed (coalesced float4 reads, swizzled scatter writes)
    for (int idx = tid; idx < 32 * K4; idx += 256) {
        int r = idx / K4;
        int k4 = idx - r * K4;
        int k = k4 * 4;
        int row = n0 + r;
        float4 v = {0.f, 0.f, 0.f, 0.f};
        if (row < NN) {
            const float* src = (k < D) ? (M + (size_t)row * D + k)
                                       : (H + (size_t)row * D + (k - D));
            v = *(const float4*)src;
        }
        int rs = r ^ ((k4 & 7) << 2);
        in_sT[(k + 0) * 32 + rs] = v.x;
        in_sT[(k + 1) * 32 + rs] = v.y;
        in_sT[(k + 2) * 32 + rs] = v.z;
        in_sT[(k + 3) * 32 + rs] = v.w;
    }
    __syncthreads();

    int c0 = (tid & 31) * 4;
    int r0 = (tid >> 5) * 4;

    float acc[4][4] = {};
#pragma unroll 8
    for (int k = 0; k < K; ++k) {
        float4 wv = *(const float4*)&WT[(size_t)k * HD + c0];
        int rs0 = r0 ^ (((k >> 2) & 7) << 2);
        float4 iv = *(const float4*)&in_sT[k * 32 + rs0];
        acc[0][0] = fmaf(iv.x, wv.x, acc[0][0]);
        acc[0][1] = fmaf(iv.x, wv.y, acc[0][1]);
        acc[0][2] = fmaf(iv.x, wv.z, acc[0][2]);
        acc[0][3] = fmaf(iv.x, wv.w, acc[0][3]);
        acc[1][0] = fmaf(iv.y, wv.x, acc[1][0]);
        acc[1][1] = fmaf(iv.y, wv.y, acc[1][1]);
        acc[1][2] = fmaf(iv.y, wv.z, acc[1][2]);
        acc[1][3] = fmaf(iv.y, wv.w, acc[1][3]);
        acc[2][0] = fmaf(iv.z, wv.x, acc[2][0]);
        acc[2][1] = fmaf(iv.z, wv.y, acc[2][1]);
        acc[2][2] = fmaf(iv.z, wv.z, acc[2][2]);
        acc[2][3] = fmaf(iv.z, wv.w, acc[2][3]);
        acc[3][0] = fmaf(iv.w, wv.x, acc[3][0]);
        acc[3][1] = fmaf(iv.w, wv.y, acc[3][1]);
        acc[3][2] = fmaf(iv.w, wv.z, acc[3][2]);
        acc[3][3] = fmaf(iv.w, wv.w, acc[3][3]);
    }

    float4 bv = *(const float4*)&bias[c0];
    float sq[4];
#pragma unroll
    for (int i = 0; i < 4; ++i) {
        acc[i][0] += bv.x; acc[i][1] += bv.y; acc[i][2] += bv.z; acc[i][3] += bv.w;
        sq[i] = acc[i][0] * acc[i][0] + acc[i][1] * acc[i][1] +
                acc[i][2] * acc[i][2] + acc[i][3] * acc[i][3];
    }
#pragma unroll
    for (int off = 1; off < 32; off <<= 1) {
#pragma unroll
        for (int i = 0; i < 4; ++i) sq[i] += __shfl_xor(sq[i], off, 64);
    }
#pragma unroll
    for (int i = 0; i < 4; ++i) {
        int row = n0 + r0 + i;
        if (row < NN) {
            float inv = 1.0f / fmaxf(sqrtf(sq[i]), 1e-12f);
            float4 o;
            o.x = acc[i][0] * inv;
            o.y = acc[i][1] * inv;
            o.z = acc[i][2] * inv;
            o.w = acc[i][3] * inv;
            if (RELU) {
                o.x = fmaxf(o.x, 0.f); o.y = fmaxf(o.y, 0.f);
                o.z = fmaxf(o.z, 0.f); o.w = fmaxf(o.w, 0.f);
            }
            *(float4*)&out[(size_t)row * HD + c0] = o;
        }
    }
}

// ---------------- launch ----------------

static inline size_t align256(size_t x) { return (x + 255) & ~(size_t)255; }

extern "C" void kernel_launch(void* const* d_in, const int* in_sizes, int n_in,
                              void* d_out, int out_size, void* d_ws, size_t ws_size,
                              hipStream_t stream) {
    const float* x   = (const float*)d_in[0];
    const int*   ei  = (const int*)d_in[1];
    const float* Wl0 = (const float*)d_in[2];
    const float* bl0 = (const float*)d_in[3];
    const float* Wr0 = (const float*)d_in[4];
    const float* Wl1 = (const float*)d_in[5];
    const float* bl1 = (const float*)d_in[6];
    const float* Wr1 = (const float*)d_in[7];
    const float* Wl2 = (const float*)d_in[8];
    const float* bl2 = (const float*)d_in[9];
    const float* Wr2 = (const float*)d_in[10];

    const int* src = ei;
    const int* dst = ei + NE;

    const int NB = (NN + 255) / 256;  // 196 scan blocks

    // workspace carve-up
    char* p = (char*)d_ws;
    size_t off = 0;
    int* fill = (int*)(p + off);        off = align256(off + (size_t)NN * 4);
    int* rowptr = (int*)(p + off);      off = align256(off + (size_t)(NN + 1) * 4);
    int* csr_src = (int*)(p + off);     off = align256(off + (size_t)NE * 4);
    float* invcnt = (float*)(p + off);  off = align256(off + (size_t)NN * 4);
    int* bsums = (int*)(p + off);       off = align256(off + (size_t)NB * 4);
    float* Hb = (float*)(p + off);      off = align256(off + (size_t)NN * HD * 4);
    float* Mb = (float*)(p + off);      off = align256(off + (size_t)NN * HD * 4);
    float* WT0 = (float*)(p + off);     off = align256(off + (size_t)2 * DIN * HD * 4);
    float* WT1 = (float*)(p + off);     off = align256(off + (size_t)2 * HD * HD * 4);
    float* WT2 = (float*)(p + off);     off = align256(off + (size_t)2 * HD * HD * 4);
    (void)ws_size; (void)n_in; (void)in_sizes; (void)out_size;

    float* out = (float*)d_out;

    // CSR build
    hipMemsetAsync(fill, 0, (size_t)NN * 4, stream);
    count_edges<<<(NE / 4 + 255) / 256, 256, 0, stream>>>(dst, fill);
    partial_scan<<<NB, 256, 0, stream>>>(fill, rowptr, bsums);
    scan_bsums<<<1, 256, 0, stream>>>(bsums, NB);
    finalize_scan<<<NB, 256, 0, stream>>>(fill, rowptr, bsums, invcnt);
    hipMemsetAsync(fill, 0, (size_t)NN * 4, stream);
    scatter_edges<<<(NE + 255) / 256, 256, 0, stream>>>(src, dst, rowptr, fill, csr_src);

    // concat-transposed weights (one kernel for all layers)
    const int WTOT = 2 * DIN * HD + 2 * 2 * HD * HD;  // 81920
    build_wt_all<<<(WTOT + 255) / 256, 256, 0, stream>>>(Wl0, Wr0, Wl1, Wr1, Wl2, Wr2,
                                                         WT0, WT1, WT2);

    const int LG = (NN + 31) / 32;  // 1563

    // layer 0: x (64ch) -> Hb
    gather_mean<DIN><<<NN, 128, 0, stream>>>(x, rowptr, csr_src, invcnt, Mb);
    linear_norm<DIN, true><<<LG, 256, 0, stream>>>(Mb, x, WT0, bl0, Hb);

    // layer 1: Hb -> Mb (row-exclusive in-place safe)
    gather_mean<HD><<<NN, 128, 0, stream>>>(Hb, rowptr, csr_src, invcnt, Mb);
    linear_norm<HD, true><<<LG, 256, 0, stream>>>(Mb, Hb, WT1, bl1, Mb);

    // layer 2: Mb -> d_out
    gather_mean<HD><<<NN, 128, 0, stream>>>(Mb, rowptr, csr_src, invcnt, Hb);
    linear_norm<HD, false><<<LG, 256, 0, stream>>>(Hb, Mb, WT2, bl2, out);
}

// Round 4
// 260.158 us; speedup vs baseline: 3.4752x; 1.5848x over previous
//
#include <hip/hip_runtime.h>

#define NN 50000
#define NNP 50016   // 1563 * 32, padded rows for the GEMM
#define NE 800000
#define DIN 64
#define HD 128

typedef __attribute__((ext_vector_type(8))) short short8;
typedef __attribute__((ext_vector_type(4))) float f32x4;
typedef __attribute__((ext_vector_type(4))) unsigned short us4;
typedef __attribute__((ext_vector_type(8))) unsigned short us8;

__device__ __forceinline__ unsigned short f2bf(float f) {
    unsigned int u = __float_as_uint(f);
    u = (u + 0x7FFFu + ((u >> 16) & 1u)) >> 16;
    return (unsigned short)u;
}
__device__ __forceinline__ float bf2f(unsigned short u) {
    return __uint_as_float(((unsigned int)u) << 16);
}

// ---------------- CSR construction ----------------

__global__ void count_edges(const int* __restrict__ dst, int* __restrict__ cnt) {
    int e4 = blockIdx.x * blockDim.x + threadIdx.x;
    if (e4 * 4 >= NE) return;
    int4 d = ((const int4*)dst)[e4];
    atomicAdd(&cnt[d.x], 1);
    atomicAdd(&cnt[d.y], 1);
    atomicAdd(&cnt[d.z], 1);
    atomicAdd(&cnt[d.w], 1);
}

__global__ void partial_scan(const int* __restrict__ cnt, int* __restrict__ rowptr,
                             int* __restrict__ bsums) {
    __shared__ int sh[256];
    int t = threadIdx.x;
    int i = blockIdx.x * 256 + t;
    int v = (i < NN) ? cnt[i] : 0;
    sh[t] = v;
    __syncthreads();
#pragma unroll
    for (int off = 1; off < 256; off <<= 1) {
        int add = (t >= off) ? sh[t - off] : 0;
        __syncthreads();
        sh[t] += add;
        __syncthreads();
    }
    if (i < NN) rowptr[i] = sh[t] - v;
    if (t == 255) bsums[blockIdx.x] = sh[255];
}

__global__ void scan_bsums(int* __restrict__ bsums, int nb) {
    __shared__ int sh[256];
    int t = threadIdx.x;
    int v = (t < nb) ? bsums[t] : 0;
    sh[t] = v;
    __syncthreads();
#pragma unroll
    for (int off = 1; off < 256; off <<= 1) {
        int add = (t >= off) ? sh[t - off] : 0;
        __syncthreads();
        sh[t] += add;
        __syncthreads();
    }
    if (t < nb) bsums[t] = sh[t] - v;
}

__global__ void finalize_scan(const int* __restrict__ cnt, int* __restrict__ rowptr,
                              const int* __restrict__ bsums, float* __restrict__ invcnt) {
    int i = blockIdx.x * 256 + threadIdx.x;
    if (i >= NN) return;
    int r = rowptr[i] + bsums[blockIdx.x];
    rowptr[i] = r;
    int c = cnt[i];
    invcnt[i] = 1.0f / (float)(c > 0 ? c : 1);
    if (i == NN - 1) rowptr[NN] = r + c;
}

__global__ void scatter_edges(const int* __restrict__ src, const int* __restrict__ dst,
                              const int* __restrict__ rowptr, int* __restrict__ fill,
                              int* __restrict__ csr_src) {
    int e = blockIdx.x * blockDim.x + threadIdx.x;
    if (e >= NE) return;
    int d = dst[e];
    int pos = rowptr[d] + atomicAdd(&fill[d], 1);
    csr_src[pos] = src[e];
}

// ---------------- prep: pack weights into MFMA B-fragment order (bf16) ----------------
// Wpk[((ks*8 + ct)*64 + lane)*8 + j] = WT[ks*32 + (lane>>4)*8 + j][ct*16 + (lane&15)]
// where WT[k][c] = k < D ? Wl[c*D+k] : Wr[c*D+k-D].

__device__ __forceinline__ void pack_one(const float* Wl, const float* Wr, int D,
                                         unsigned short* Wpk, int i) {
    int j = i & 7;
    int lane = (i >> 3) & 63;
    int ct = (i >> 9) & 7;
    int ks = i >> 12;
    int k = ks * 32 + ((lane >> 4) << 3) + j;
    int c = ct * 16 + (lane & 15);
    float v = (k < D) ? Wl[c * D + k] : Wr[c * D + (k - D)];
    Wpk[i] = f2bf(v);
}

__global__ void pack_weights(const float* __restrict__ Wl0, const float* __restrict__ Wr0,
                             const float* __restrict__ Wl1, const float* __restrict__ Wr1,
                             const float* __restrict__ Wl2, const float* __restrict__ Wr2,
                             unsigned short* __restrict__ Wpk0,
                             unsigned short* __restrict__ Wpk1,
                             unsigned short* __restrict__ Wpk2) {
    const int S0 = 2 * DIN * HD;   // 16384
    const int S12 = 2 * HD * HD;   // 32768
    int i = blockIdx.x * blockDim.x + threadIdx.x;
    if (i < S0) { pack_one(Wl0, Wr0, DIN, Wpk0, i); return; }
    int j = i - S0;
    if (j < S12) { pack_one(Wl1, Wr1, HD, Wpk1, j); return; }
    int m = j - S12;
    if (m < S12) pack_one(Wl2, Wr2, HD, Wpk2, m);
}

// x f32 [NN][64] -> bf16 into A0[:, 64:128] (row stride 128)
__global__ void conv_x(const float* __restrict__ x, unsigned short* __restrict__ A0) {
    int i = blockIdx.x * blockDim.x + threadIdx.x;  // NN*16 chunks
    if (i >= NN * 16) return;
    int row = i >> 4, c4 = i & 15;
    float4 v = ((const float4*)(x + (size_t)row * DIN))[c4];
    us4 o = {f2bf(v.x), f2bf(v.y), f2bf(v.z), f2bf(v.w)};
    *(us4*)(A0 + (size_t)row * 128 + 64 + c4 * 4) = o;
}

// ---------------- gather-mean layer 0: f32 x in, bf16 mean out (A0[:,0:64]) ----------------

__global__ void gather_mean_x(const float* __restrict__ x, const int* __restrict__ rowptr,
                              const int* __restrict__ csr_src, const float* __restrict__ invcnt,
                              unsigned short* __restrict__ A0) {
    __shared__ float4 red[128];
    int n = blockIdx.x, t = threadIdx.x;
    int c4 = t & 15;   // 16 chunks x 4 ch = 64
    int g = t >> 4;    // 8 edge groups
    int beg = rowptr[n], end = rowptr[n + 1];
    float4 acc = {0.f, 0.f, 0.f, 0.f};
    for (int e = beg + g; e < end; e += 8) {
        float4 v = ((const float4*)(x + (size_t)csr_src[e] * DIN))[c4];
        acc.x += v.x; acc.y += v.y; acc.z += v.z; acc.w += v.w;
    }
    red[t] = acc;
    __syncthreads();
    if (g == 0) {
#pragma unroll
        for (int j = 1; j < 8; ++j) {
            float4 v = red[j * 16 + c4];
            acc.x += v.x; acc.y += v.y; acc.z += v.z; acc.w += v.w;
        }
        float ic = invcnt[n];
        us4 o = {f2bf(acc.x * ic), f2bf(acc.y * ic), f2bf(acc.z * ic), f2bf(acc.w * ic)};
        *(us4*)(A0 + (size_t)n * 128 + c4 * 4) = o;
    }
}

// ---------------- gather-mean layers 1,2: bf16 h in (A12[:,128:256]), bf16 mean out ----------------

__global__ void gather_mean_h(const unsigned short* __restrict__ A12,
                              const int* __restrict__ rowptr, const int* __restrict__ csr_src,
                              const float* __restrict__ invcnt, unsigned short* __restrict__ Am) {
    __shared__ float red[128 * 8];
    int n = blockIdx.x, t = threadIdx.x;
    int c8 = t & 15;   // 16 chunks x 8 ch = 128
    int g = t >> 4;    // 8 edge groups
    int beg = rowptr[n], end = rowptr[n + 1];
    float acc[8] = {};
    const unsigned short* hbase = A12 + 128 + (size_t)c8 * 8;
    for (int e = beg + g; e < end; e += 8) {
        us8 v = *(const us8*)(hbase + (size_t)csr_src[e] * 256);
#pragma unroll
        for (int j = 0; j < 8; ++j) acc[j] += bf2f(v[j]);
    }
#pragma unroll
    for (int j = 0; j < 8; ++j) red[t * 8 + j] = acc[j];
    __syncthreads();
    if (g == 0) {
#pragma unroll
        for (int grp = 1; grp < 8; ++grp)
#pragma unroll
            for (int j = 0; j < 8; ++j) acc[j] += red[(grp * 16 + c8) * 8 + j];
        float ic = invcnt[n];
        us8 o;
#pragma unroll
        for (int j = 0; j < 8; ++j) o[j] = f2bf(acc[j] * ic);
        *(us8*)(Am + (size_t)n * 256 + c8 * 8) = o;
    }
}

// ---------------- fused MFMA GEMM + bias + L2 norm + (ReLU) ----------------
// C[NNP x 128] = A[NNP x K] * WT[K x 128]; block = 32 rows x 128 cols, 4 waves.
// Wave (rg,cg): rows r0+rg*16..+16, cols cg*64..+64 as 4 MFMA 16x16 tiles.
// A-frag: row=lane&15, k=(lane>>4)*8+j (16B/lane, contiguous).
// B-frag: pre-packed (pack_weights) so each lane loads 16B contiguous.
// C/D: col=lane&15, row=(lane>>4)*4+reg.

template <int K, bool RELU, bool F32OUT, bool BF16H>
__global__ __launch_bounds__(256) void linear_mfma(
    const unsigned short* __restrict__ A, const unsigned short* __restrict__ Wpk,
    const float* __restrict__ bias, float* __restrict__ outF,
    unsigned short* __restrict__ Hn /* h-part base (stride 256) */) {
    constexpr int NK = K / 32;
    __shared__ float rsum[2][32];
    int tid = threadIdx.x;
    int lane = tid & 63, w = tid >> 6;
    int rg = w >> 1, cg = w & 1;
    int r0 = blockIdx.x * 32 + rg * 16;
    int row_l = lane & 15, kb = lane >> 4;

    const unsigned short* Arow = A + (size_t)(r0 + row_l) * K + kb * 8;
    const unsigned short* Wp = Wpk + ((size_t)(cg * 4) * 64 + lane) * 8;

    f32x4 acc[4] = {{0.f, 0.f, 0.f, 0.f}, {0.f, 0.f, 0.f, 0.f},
                    {0.f, 0.f, 0.f, 0.f}, {0.f, 0.f, 0.f, 0.f}};
#pragma unroll
    for (int ks = 0; ks < NK; ++ks) {
        short8 a = *(const short8*)(Arow + ks * 32);
#pragma unroll
        for (int t = 0; t < 4; ++t) {
            short8 b = *(const short8*)(Wp + ((size_t)ks * 8 + t) * 64 * 8);
            acc[t] = __builtin_amdgcn_mfma_f32_16x16x32_bf16(a, b, acc[t], 0, 0, 0);
        }
    }

    // bias + per-row sum of squares (rows kb*4+r, cols cg*64 + t*16 + row_l)
    float sq[4] = {0.f, 0.f, 0.f, 0.f};
#pragma unroll
    for (int t = 0; t < 4; ++t) {
        float bv = bias[cg * 64 + t * 16 + row_l];
#pragma unroll
        for (int r = 0; r < 4; ++r) {
            acc[t][r] += bv;
            sq[r] = fmaf(acc[t][r], acc[t][r], sq[r]);
        }
    }
#pragma unroll
    for (int off = 1; off < 16; off <<= 1)
#pragma unroll
        for (int r = 0; r < 4; ++r) sq[r] += __shfl_xor(sq[r], off, 64);

    if (row_l == 0) {
#pragma unroll
        for (int r = 0; r < 4; ++r) rsum[cg][rg * 16 + kb * 4 + r] = sq[r];
    }
    __syncthreads();  // also orders all A reads before the BF16H in-place writes

    int rbase = rg * 16 + kb * 4;
#pragma unroll
    for (int r = 0; r < 4; ++r) {
        int row = r0 + kb * 4 + r;
        if (row >= NN) continue;
        float n2 = rsum[0][rbase + r] + rsum[1][rbase + r];
        float inv = 1.0f / fmaxf(sqrtf(n2), 1e-12f);
#pragma unroll
        for (int t = 0; t < 4; ++t) {
            float v = acc[t][r] * inv;
            if (RELU) v = fmaxf(v, 0.f);
            int c = cg * 64 + t * 16 + row_l;
            if (F32OUT) outF[(size_t)row * HD + c] = v;
            if (BF16H) Hn[(size_t)row * 256 + c] = f2bf(v);
        }
    }
}

// ---------------- launch ----------------

static inline size_t align256(size_t x) { return (x + 255) & ~(size_t)255; }

extern "C" void kernel_launch(void* const* d_in, const int* in_sizes, int n_in,
                              void* d_out, int out_size, void* d_ws, size_t ws_size,
                              hipStream_t stream) {
    const float* x   = (const float*)d_in[0];
    const int*   ei  = (const int*)d_in[1];
    const float* Wl0 = (const float*)d_in[2];
    const float* bl0 = (const float*)d_in[3];
    const float* Wr0 = (const float*)d_in[4];
    const float* Wl1 = (const float*)d_in[5];
    const float* bl1 = (const float*)d_in[6];
    const float* Wr1 = (const float*)d_in[7];
    const float* Wl2 = (const float*)d_in[8];
    const float* bl2 = (const float*)d_in[9];
    const float* Wr2 = (const float*)d_in[10];

    const int* src = ei;
    const int* dst = ei + NE;

    const int NB = (NN + 255) / 256;  // 196

    // workspace carve-up
    char* p = (char*)d_ws;
    size_t off = 0;
    int* fill = (int*)(p + off);            off = align256(off + (size_t)NN * 4);
    int* rowptr = (int*)(p + off);          off = align256(off + (size_t)(NN + 1) * 4);
    int* csr_src = (int*)(p + off);         off = align256(off + (size_t)NE * 4);
    float* invcnt = (float*)(p + off);      off = align256(off + (size_t)NN * 4);
    int* bsums = (int*)(p + off);           off = align256(off + (size_t)NB * 4);
    unsigned short* A0 = (unsigned short*)(p + off);   off = align256(off + (size_t)NNP * 128 * 2);
    unsigned short* A12 = (unsigned short*)(p + off);  off = align256(off + (size_t)NNP * 256 * 2);
    unsigned short* Wpk0 = (unsigned short*)(p + off); off = align256(off + (size_t)2 * DIN * HD * 2);
    unsigned short* Wpk1 = (unsigned short*)(p + off); off = align256(off + (size_t)2 * HD * HD * 2);
    unsigned short* Wpk2 = (unsigned short*)(p + off); off = align256(off + (size_t)2 * HD * HD * 2);
    (void)ws_size; (void)n_in; (void)in_sizes; (void)out_size;

    float* out = (float*)d_out;

    // CSR build
    hipMemsetAsync(fill, 0, (size_t)NN * 4, stream);
    count_edges<<<(NE / 4 + 255) / 256, 256, 0, stream>>>(dst, fill);
    partial_scan<<<NB, 256, 0, stream>>>(fill, rowptr, bsums);
    scan_bsums<<<1, 256, 0, stream>>>(bsums, NB);
    finalize_scan<<<NB, 256, 0, stream>>>(fill, rowptr, bsums, invcnt);
    hipMemsetAsync(fill, 0, (size_t)NN * 4, stream);
    scatter_edges<<<(NE + 255) / 256, 256, 0, stream>>>(src, dst, rowptr, fill, csr_src);

    // prep: packed weights + x -> bf16
    const int WTOT = 2 * DIN * HD + 2 * 2 * HD * HD;  // 81920
    pack_weights<<<(WTOT + 255) / 256, 256, 0, stream>>>(Wl0, Wr0, Wl1, Wr1, Wl2, Wr2,
                                                         Wpk0, Wpk1, Wpk2);
    conv_x<<<(NN * 16 + 255) / 256, 256, 0, stream>>>(x, A0);

    const int LG = NNP / 32;  // 1563

    // layer 0: gather x -> A0 mean part; GEMM K=128 -> h0 bf16 into A12[:,128:256]
    gather_mean_x<<<NN, 128, 0, stream>>>(x, rowptr, csr_src, invcnt, A0);
    linear_mfma<2 * DIN, true, false, true><<<LG, 256, 0, stream>>>(
        A0, Wpk0, bl0, nullptr, A12 + 128);

    // layer 1: gather h0 (bf16) -> A12 mean part; GEMM K=256 -> h1 bf16 (in place)
    gather_mean_h<<<NN, 128, 0, stream>>>(A12, rowptr, csr_src, invcnt, A12);
    linear_mfma<2 * HD, true, false, true><<<LG, 256, 0, stream>>>(
        A12, Wpk1, bl1, nullptr, A12 + 128);

    // layer 2: gather h1 -> A12 mean part; GEMM K=256 -> f32 d_out
    gather_mean_h<<<NN, 128, 0, stream>>>(A12, rowptr, csr_src, invcnt, A12);
    linear_mfma<2 * HD, false, true, false><<<LG, 256, 0, stream>>>(
        A12, Wpk2, bl2, out, nullptr);
}

// Round 5
// 204.758 us; speedup vs baseline: 4.4155x; 1.2706x over previous
//
#include <hip/hip_runtime.h>

#define NN 50000
#define NNP 50016   // 1563 * 32, padded rows for the GEMM
#define NE 800000
#define DIN 64
#define HD 128
#define NBUK 196            // ceil(NN/256) coarse buckets (dst>>8)
#define SB 196              // ceil(NE/4096) scatter chunks
#define BCAP 12288          // build_csr LDS capacity (edges per bucket fast path)

typedef __attribute__((ext_vector_type(8))) short short8;
typedef __attribute__((ext_vector_type(4))) float f32x4;
typedef __attribute__((ext_vector_type(4))) unsigned short us4;
typedef __attribute__((ext_vector_type(8))) unsigned short us8;

__device__ __forceinline__ unsigned short f2bf(float f) {
    unsigned int u = __float_as_uint(f);
    u = (u + 0x7FFFu + ((u >> 16) & 1u)) >> 16;
    return (unsigned short)u;
}
__device__ __forceinline__ float bf2f(unsigned short u) {
    return __uint_as_float(((unsigned int)u) << 16);
}

// inclusive Hillis-Steele scan over a[256]; all 256 threads must execute
#define LDS_SCAN256(a, t)                                 \
    for (int off_ = 1; off_ < 256; off_ <<= 1) {          \
        int add_ = ((t) >= off_) ? (a)[(t) - off_] : 0;   \
        __syncthreads();                                  \
        (a)[t] += add_;                                   \
        __syncthreads();                                  \
    }

// ---------------- CSR via two-level LDS counting sort ----------------

__global__ __launch_bounds__(256) void bucket_count(const int* __restrict__ dst,
                                                    int* __restrict__ bcnt) {
    __shared__ int lc[256];
    int t = threadIdx.x;
    lc[t] = 0;
    __syncthreads();
    int base = blockIdx.x * 4096 + t * 16;
#pragma unroll
    for (int j = 0; j < 4; ++j) {
        int e = base + j * 4;
        if (e < NE) {
            int4 d = *(const int4*)(dst + e);
            atomicAdd(&lc[d.x >> 8], 1);
            atomicAdd(&lc[d.y >> 8], 1);
            atomicAdd(&lc[d.z >> 8], 1);
            atomicAdd(&lc[d.w >> 8], 1);
        }
    }
    __syncthreads();
    if (t < NBUK && lc[t] > 0) atomicAdd(&bcnt[t], lc[t]);
}

__global__ __launch_bounds__(256) void bucket_scan(const int* __restrict__ bcnt,
                                                   int* __restrict__ bbase,
                                                   int* __restrict__ rowptr) {
    __shared__ int sh[256];
    int t = threadIdx.x;
    int v = (t < NBUK) ? bcnt[t] : 0;
    sh[t] = v;
    __syncthreads();
    LDS_SCAN256(sh, t);
    if (t < NBUK) bbase[t] = sh[t] - v;   // exclusive
    if (t == NBUK - 1) bbase[NBUK] = sh[t];
    if (t == 0) rowptr[NN] = NE;
}

__global__ __launch_bounds__(256) void bucket_scatter(
    const int* __restrict__ src, const int* __restrict__ dst,
    const int* __restrict__ bbase, int* __restrict__ bfill,
    int2* __restrict__ pairs) {
    __shared__ int cnt[256];
    __shared__ int incl[256];
    __shared__ int lfill[256];
    __shared__ int rung[256];
    __shared__ int2 buf[4096];
    int t = threadIdx.x;
    cnt[t] = 0;
    lfill[t] = 0;
    __syncthreads();
    int base = blockIdx.x * 4096 + t * 16;
    // phase A: local bucket histogram
#pragma unroll
    for (int j = 0; j < 4; ++j) {
        int e = base + j * 4;
        if (e < NE) {
            int4 d = *(const int4*)(dst + e);
            atomicAdd(&cnt[d.x >> 8], 1);
            atomicAdd(&cnt[d.y >> 8], 1);
            atomicAdd(&cnt[d.z >> 8], 1);
            atomicAdd(&cnt[d.w >> 8], 1);
        }
    }
    __syncthreads();
    incl[t] = cnt[t];
    __syncthreads();
    LDS_SCAN256(incl, t);
    // phase B: allocate one global run per non-empty bucket
    int c = cnt[t];
    if (t < NBUK && c > 0) rung[t] = bbase[t] + atomicAdd(&bfill[t], c);
    __syncthreads();
    // phase C: stable-ish local scatter into LDS, grouped by bucket
#pragma unroll
    for (int j = 0; j < 4; ++j) {
        int e = base + j * 4;
        if (e < NE) {
            int4 s4 = *(const int4*)(src + e);
            int4 d4 = *(const int4*)(dst + e);
            int ss[4] = {s4.x, s4.y, s4.z, s4.w};
            int dd[4] = {d4.x, d4.y, d4.z, d4.w};
#pragma unroll
            for (int q = 0; q < 4; ++q) {
                int k = dd[q] >> 8;
                int p = (incl[k] - cnt[k]) + atomicAdd(&lfill[k], 1);
                buf[p] = {ss[q], dd[q]};
            }
        }
    }
    __syncthreads();
    // phase D: coalesced run writes
    int n = min(4096, NE - blockIdx.x * 4096);
    for (int i = t; i < n; i += 256) {
        int2 pr = buf[i];
        int k = pr.y >> 8;
        pairs[rung[k] + (i - (incl[k] - cnt[k]))] = pr;
    }
}

__global__ __launch_bounds__(256) void build_csr(
    const int2* __restrict__ pairs, const int* __restrict__ bbase,
    int* __restrict__ rowptr, float* __restrict__ invcnt,
    int* __restrict__ csr_src) {
    __shared__ int cnt[256];
    __shared__ int incl[256];
    __shared__ int lfill[256];
    __shared__ int sbuf[BCAP];
    int b = blockIdx.x, t = threadIdx.x;
    int pbeg = bbase[b], pend = bbase[b + 1];
    int sz = pend - pbeg;
    cnt[t] = 0;
    lfill[t] = 0;
    __syncthreads();
    for (int i = t; i < sz; i += 256)
        atomicAdd(&cnt[pairs[pbeg + i].y & 255], 1);
    __syncthreads();
    incl[t] = cnt[t];
    __syncthreads();
    LDS_SCAN256(incl, t);
    int node = b * 256 + t;
    int c = cnt[t];
    if (node < NN) {
        rowptr[node] = pbeg + incl[t] - c;   // global exclusive position
        invcnt[node] = 1.0f / (float)(c > 0 ? c : 1);
    }
    if (sz <= BCAP) {
        for (int i = t; i < sz; i += 256) {
            int2 pr = pairs[pbeg + i];
            int ld = pr.y & 255;
            sbuf[(incl[ld] - cnt[ld]) + atomicAdd(&lfill[ld], 1)] = pr.x;
        }
        __syncthreads();
        for (int i = t; i < sz; i += 256) csr_src[pbeg + i] = sbuf[i];
    } else {  // safety fallback (not hit for uniform dst)
        for (int i = t; i < sz; i += 256) {
            int2 pr = pairs[pbeg + i];
            int ld = pr.y & 255;
            csr_src[pbeg + (incl[ld] - cnt[ld]) + atomicAdd(&lfill[ld], 1)] = pr.x;
        }
    }
}

// ---------------- prep: pack weights into MFMA B-fragment order (bf16) ----------------

__device__ __forceinline__ void pack_one(const float* Wl, const float* Wr, int D,
                                         unsigned short* Wpk, int i) {
    int j = i & 7;
    int lane = (i >> 3) & 63;
    int ct = (i >> 9) & 7;
    int ks = i >> 12;
    int k = ks * 32 + ((lane >> 4) << 3) + j;
    int c = ct * 16 + (lane & 15);
    float v = (k < D) ? Wl[c * D + k] : Wr[c * D + (k - D)];
    Wpk[i] = f2bf(v);
}

__global__ void pack_weights(const float* __restrict__ Wl0, const float* __restrict__ Wr0,
                             const float* __restrict__ Wl1, const float* __restrict__ Wr1,
                             const float* __restrict__ Wl2, const float* __restrict__ Wr2,
                             unsigned short* __restrict__ Wpk0,
                             unsigned short* __restrict__ Wpk1,
                             unsigned short* __restrict__ Wpk2) {
    const int S0 = 2 * DIN * HD;   // 16384
    const int S12 = 2 * HD * HD;   // 32768
    int i = blockIdx.x * blockDim.x + threadIdx.x;
    if (i < S0) { pack_one(Wl0, Wr0, DIN, Wpk0, i); return; }
    int j = i - S0;
    if (j < S12) { pack_one(Wl1, Wr1, HD, Wpk1, j); return; }
    int m = j - S12;
    if (m < S12) pack_one(Wl2, Wr2, HD, Wpk2, m);
}

// x f32 [NN][64] -> bf16 into A0[:, 64:128] (row stride 128)
__global__ void conv_x(const float* __restrict__ x, unsigned short* __restrict__ A0) {
    int i = blockIdx.x * blockDim.x + threadIdx.x;  // NN*16 chunks
    if (i >= NN * 16) return;
    int row = i >> 4, c4 = i & 15;
    float4 v = ((const float4*)(x + (size_t)row * DIN))[c4];
    us4 o = {f2bf(v.x), f2bf(v.y), f2bf(v.z), f2bf(v.w)};
    *(us4*)(A0 + (size_t)row * 128 + 64 + c4 * 4) = o;
}

// ---------------- gather-mean layer 0: f32 x in, bf16 mean out (A0[:,0:64]) ----------------

__global__ void gather_mean_x(const float* __restrict__ x, const int* __restrict__ rowptr,
                              const int* __restrict__ csr_src, const float* __restrict__ invcnt,
                              unsigned short* __restrict__ A0) {
    __shared__ float4 red[128];
    int n = blockIdx.x, t = threadIdx.x;
    int c4 = t & 15;
    int g = t >> 4;
    int beg = rowptr[n], end = rowptr[n + 1];
    float4 acc = {0.f, 0.f, 0.f, 0.f};
    for (int e = beg + g; e < end; e += 8) {
        float4 v = ((const float4*)(x + (size_t)csr_src[e] * DIN))[c4];
        acc.x += v.x; acc.y += v.y; acc.z += v.z; acc.w += v.w;
    }
    red[t] = acc;
    __syncthreads();
    if (g == 0) {
#pragma unroll
        for (int j = 1; j < 8; ++j) {
            float4 v = red[j * 16 + c4];
            acc.x += v.x; acc.y += v.y; acc.z += v.z; acc.w += v.w;
        }
        float ic = invcnt[n];
        us4 o = {f2bf(acc.x * ic), f2bf(acc.y * ic), f2bf(acc.z * ic), f2bf(acc.w * ic)};
        *(us4*)(A0 + (size_t)n * 128 + c4 * 4) = o;
    }
}

// ---------------- gather-mean layers 1,2: bf16 h in (A12[:,128:256]), bf16 mean out ----------------

__global__ void gather_mean_h(const unsigned short* __restrict__ A12,
                              const int* __restrict__ rowptr, const int* __restrict__ csr_src,
                              const float* __restrict__ invcnt, unsigned short* __restrict__ Am) {
    __shared__ float red[128 * 8];
    int n = blockIdx.x, t = threadIdx.x;
    int c8 = t & 15;
    int g = t >> 4;
    int beg = rowptr[n], end = rowptr[n + 1];
    float acc[8] = {};
    const unsigned short* hbase = A12 + 128 + (size_t)c8 * 8;
    for (int e = beg + g; e < end; e += 8) {
        us8 v = *(const us8*)(hbase + (size_t)csr_src[e] * 256);
#pragma unroll
        for (int j = 0; j < 8; ++j) acc[j] += bf2f(v[j]);
    }
#pragma unroll
    for (int j = 0; j < 8; ++j) red[t * 8 + j] = acc[j];
    __syncthreads();
    if (g == 0) {
#pragma unroll
        for (int grp = 1; grp < 8; ++grp)
#pragma unroll
            for (int j = 0; j < 8; ++j) acc[j] += red[(grp * 16 + c8) * 8 + j];
        float ic = invcnt[n];
        us8 o;
#pragma unroll
        for (int j = 0; j < 8; ++j) o[j] = f2bf(acc[j] * ic);
        *(us8*)(Am + (size_t)n * 256 + c8 * 8) = o;
    }
}

// ---------------- fused MFMA GEMM + bias + L2 norm + (ReLU) ----------------

template <int K, bool RELU, bool F32OUT, bool BF16H>
__global__ __launch_bounds__(256) void linear_mfma(
    const unsigned short* __restrict__ A, const unsigned short* __restrict__ Wpk,
    const float* __restrict__ bias, float* __restrict__ outF,
    unsigned short* __restrict__ Hn /* h-part base (stride 256) */) {
    constexpr int NK = K / 32;
    __shared__ float rsum[2][32];
    int tid = threadIdx.x;
    int lane = tid & 63, w = tid >> 6;
    int rg = w >> 1, cg = w & 1;
    int r0 = blockIdx.x * 32 + rg * 16;
    int row_l = lane & 15, kb = lane >> 4;

    const unsigned short* Arow = A + (size_t)(r0 + row_l) * K + kb * 8;
    const unsigned short* Wp = Wpk + ((size_t)(cg * 4) * 64 + lane) * 8;

    f32x4 acc[4] = {{0.f, 0.f, 0.f, 0.f}, {0.f, 0.f, 0.f, 0.f},
                    {0.f, 0.f, 0.f, 0.f}, {0.f, 0.f, 0.f, 0.f}};
#pragma unroll
    for (int ks = 0; ks < NK; ++ks) {
        short8 a = *(const short8*)(Arow + ks * 32);
#pragma unroll
        for (int t = 0; t < 4; ++t) {
            short8 b = *(const short8*)(Wp + ((size_t)ks * 8 + t) * 64 * 8);
            acc[t] = __builtin_amdgcn_mfma_f32_16x16x32_bf16(a, b, acc[t], 0, 0, 0);
        }
    }

    float sq[4] = {0.f, 0.f, 0.f, 0.f};
#pragma unroll
    for (int t = 0; t < 4; ++t) {
        float bv = bias[cg * 64 + t * 16 + row_l];
#pragma unroll
        for (int r = 0; r < 4; ++r) {
            acc[t][r] += bv;
            sq[r] = fmaf(acc[t][r], acc[t][r], sq[r]);
        }
    }
#pragma unroll
    for (int off = 1; off < 16; off <<= 1)
#pragma unroll
        for (int r = 0; r < 4; ++r) sq[r] += __shfl_xor(sq[r], off, 64);

    if (row_l == 0) {
#pragma unroll
        for (int r = 0; r < 4; ++r) rsum[cg][rg * 16 + kb * 4 + r] = sq[r];
    }
    __syncthreads();  // also orders all A reads before the BF16H in-place writes

    int rbase = rg * 16 + kb * 4;
#pragma unroll
    for (int r = 0; r < 4; ++r) {
        int row = r0 + kb * 4 + r;
        if (row >= NN) continue;
        float n2 = rsum[0][rbase + r] + rsum[1][rbase + r];
        float inv = 1.0f / fmaxf(sqrtf(n2), 1e-12f);
#pragma unroll
        for (int t = 0; t < 4; ++t) {
            float v = acc[t][r] * inv;
            if (RELU) v = fmaxf(v, 0.f);
            int c = cg * 64 + t * 16 + row_l;
            if (F32OUT) outF[(size_t)row * HD + c] = v;
            if (BF16H) Hn[(size_t)row * 256 + c] = f2bf(v);
        }
    }
}

// ---------------- launch ----------------

static inline size_t align256(size_t x) { return (x + 255) & ~(size_t)255; }

extern "C" void kernel_launch(void* const* d_in, const int* in_sizes, int n_in,
                              void* d_out, int out_size, void* d_ws, size_t ws_size,
                              hipStream_t stream) {
    const float* x   = (const float*)d_in[0];
    const int*   ei  = (const int*)d_in[1];
    const float* Wl0 = (const float*)d_in[2];
    const float* bl0 = (const float*)d_in[3];
    const float* Wr0 = (const float*)d_in[4];
    const float* Wl1 = (const float*)d_in[5];
    const float* bl1 = (const float*)d_in[6];
    const float* Wr1 = (const float*)d_in[7];
    const float* Wl2 = (const float*)d_in[8];
    const float* bl2 = (const float*)d_in[9];
    const float* Wr2 = (const float*)d_in[10];

    const int* src = ei;
    const int* dst = ei + NE;

    // workspace carve-up
    char* p = (char*)d_ws;
    size_t off = 0;
    int* meta = (int*)(p + off);            off = align256(off + 512 * 4);         // bcnt[256] + bfill[256]
    int* bbase = (int*)(p + off);           off = align256(off + 256 * 4);
    int* rowptr = (int*)(p + off);          off = align256(off + (size_t)(NN + 1) * 4);
    int* csr_src = (int*)(p + off);         off = align256(off + (size_t)NE * 4);
    float* invcnt = (float*)(p + off);      off = align256(off + (size_t)NN * 4);
    unsigned short* A0 = (unsigned short*)(p + off);   off = align256(off + (size_t)NNP * 128 * 2);
    unsigned short* A12 = (unsigned short*)(p + off);  off = align256(off + (size_t)NNP * 256 * 2);
    unsigned short* Wpk0 = (unsigned short*)(p + off); off = align256(off + (size_t)2 * DIN * HD * 2);
    unsigned short* Wpk1 = (unsigned short*)(p + off); off = align256(off + (size_t)2 * HD * HD * 2);
    unsigned short* Wpk2 = (unsigned short*)(p + off); off = align256(off + (size_t)2 * HD * HD * 2);
    (void)ws_size; (void)n_in; (void)in_sizes; (void)out_size;

    int* bcnt = meta;
    int* bfill = meta + 256;
    int2* pairs = (int2*)A0;  // 6.4MB alias inside A0's 12.8MB; consumed before conv_x/gather write A0

    float* out = (float*)d_out;

    // CSR build: two-level LDS counting sort (coalesced writes, no cross-XCD line sharing)
    hipMemsetAsync(meta, 0, 512 * 4, stream);
    bucket_count<<<SB, 256, 0, stream>>>(dst, bcnt);
    bucket_scan<<<1, 256, 0, stream>>>(bcnt, bbase, rowptr);
    bucket_scatter<<<SB, 256, 0, stream>>>(src, dst, bbase, bfill, pairs);
    build_csr<<<NBUK, 256, 0, stream>>>(pairs, bbase, rowptr, invcnt, csr_src);

    // prep: packed weights + x -> bf16 (after build_csr: pairs aliases A0)
    const int WTOT = 2 * DIN * HD + 2 * 2 * HD * HD;  // 81920
    pack_weights<<<(WTOT + 255) / 256, 256, 0, stream>>>(Wl0, Wr0, Wl1, Wr1, Wl2, Wr2,
                                                         Wpk0, Wpk1, Wpk2);
    conv_x<<<(NN * 16 + 255) / 256, 256, 0, stream>>>(x, A0);

    const int LG = NNP / 32;  // 1563

    // layer 0: gather x -> A0 mean part; GEMM K=128 -> h0 bf16 into A12[:,128:256]
    gather_mean_x<<<NN, 128, 0, stream>>>(x, rowptr, csr_src, invcnt, A0);
    linear_mfma<2 * DIN, true, false, true><<<LG, 256, 0, stream>>>(
        A0, Wpk0, bl0, nullptr, A12 + 128);

    // layer 1: gather h0 (bf16) -> A12 mean part; GEMM K=256 -> h1 bf16 (in place)
    gather_mean_h<<<NN, 128, 0, stream>>>(A12, rowptr, csr_src, invcnt, A12);
    linear_mfma<2 * HD, true, false, true><<<LG, 256, 0, stream>>>(
        A12, Wpk1, bl1, nullptr, A12 + 128);

    // layer 2: gather h1 -> A12 mean part; GEMM K=256 -> f32 d_out
    gather_mean_h<<<NN, 128, 0, stream>>>(A12, rowptr, csr_src, invcnt, A12);
    linear_mfma<2 * HD, false, true, false><<<LG, 256, 0, stream>>>(
        A12, Wpk2, bl2, out, nullptr);
}

// Round 6
// 203.589 us; speedup vs baseline: 4.4409x; 1.0057x over previous
//
#include <hip/hip_runtime.h>

#define NN 50000
#define NNP 50016   // 1563 * 32, padded rows for the GEMM
#define NE 800000
#define DIN 64
#define HD 128
#define NBUK 196            // ceil(NN/256) coarse buckets (dst>>8)
#define SB 196              // ceil(NE/4096) scatter chunks
#define BCAP 12288          // build_csr LDS capacity (edges per bucket fast path)

typedef __attribute__((ext_vector_type(8))) short short8;
typedef __attribute__((ext_vector_type(4))) float f32x4;
typedef __attribute__((ext_vector_type(4))) unsigned short us4;
typedef __attribute__((ext_vector_type(8))) unsigned short us8;

__device__ __forceinline__ unsigned short f2bf(float f) {
    unsigned int u = __float_as_uint(f);
    u = (u + 0x7FFFu + ((u >> 16) & 1u)) >> 16;
    return (unsigned short)u;
}
__device__ __forceinline__ float bf2f(unsigned short u) {
    return __uint_as_float(((unsigned int)u) << 16);
}

// inclusive Hillis-Steele scan over a[256]; all 256 threads must execute
#define LDS_SCAN256(a, t)                                 \
    for (int off_ = 1; off_ < 256; off_ <<= 1) {          \
        int add_ = ((t) >= off_) ? (a)[(t) - off_] : 0;   \
        __syncthreads();                                  \
        (a)[t] += add_;                                   \
        __syncthreads();                                  \
    }

// ---------------- CSR via two-level LDS counting sort ----------------

__global__ void zero_meta(int* __restrict__ meta) {
    meta[threadIdx.x] = 0;  // 512 threads: bcnt[256] + bfill[256]
}

__global__ __launch_bounds__(256) void bucket_count(const int* __restrict__ dst,
                                                    int* __restrict__ bcnt) {
    __shared__ int lc[256];
    int t = threadIdx.x;
    lc[t] = 0;
    __syncthreads();
    int base = blockIdx.x * 4096 + t * 16;
#pragma unroll
    for (int j = 0; j < 4; ++j) {
        int e = base + j * 4;
        if (e < NE) {
            int4 d = *(const int4*)(dst + e);
            atomicAdd(&lc[d.x >> 8], 1);
            atomicAdd(&lc[d.y >> 8], 1);
            atomicAdd(&lc[d.z >> 8], 1);
            atomicAdd(&lc[d.w >> 8], 1);
        }
    }
    __syncthreads();
    if (t < NBUK && lc[t] > 0) atomicAdd(&bcnt[t], lc[t]);
}

__global__ __launch_bounds__(256) void bucket_scan(const int* __restrict__ bcnt,
                                                   int* __restrict__ bbase,
                                                   int* __restrict__ rowptr) {
    __shared__ int sh[256];
    int t = threadIdx.x;
    int v = (t < NBUK) ? bcnt[t] : 0;
    sh[t] = v;
    __syncthreads();
    LDS_SCAN256(sh, t);
    if (t < NBUK) bbase[t] = sh[t] - v;   // exclusive
    if (t == NBUK - 1) bbase[NBUK] = sh[t];
    if (t == 0) rowptr[NN] = NE;
}

__global__ __launch_bounds__(256) void bucket_scatter(
    const int* __restrict__ src, const int* __restrict__ dst,
    const int* __restrict__ bbase, int* __restrict__ bfill,
    int2* __restrict__ pairs) {
    __shared__ int cnt[256];
    __shared__ int incl[256];
    __shared__ int lfill[256];
    __shared__ int rung[256];
    __shared__ int2 buf[4096];
    int t = threadIdx.x;
    cnt[t] = 0;
    lfill[t] = 0;
    __syncthreads();
    int base = blockIdx.x * 4096 + t * 16;
    // phase A: local bucket histogram
#pragma unroll
    for (int j = 0; j < 4; ++j) {
        int e = base + j * 4;
        if (e < NE) {
            int4 d = *(const int4*)(dst + e);
            atomicAdd(&cnt[d.x >> 8], 1);
            atomicAdd(&cnt[d.y >> 8], 1);
            atomicAdd(&cnt[d.z >> 8], 1);
            atomicAdd(&cnt[d.w >> 8], 1);
        }
    }
    __syncthreads();
    incl[t] = cnt[t];
    __syncthreads();
    LDS_SCAN256(incl, t);
    // phase B: allocate one global run per non-empty bucket
    int c = cnt[t];
    if (t < NBUK && c > 0) rung[t] = bbase[t] + atomicAdd(&bfill[t], c);
    __syncthreads();
    // phase C: local scatter into LDS, grouped by bucket
#pragma unroll
    for (int j = 0; j < 4; ++j) {
        int e = base + j * 4;
        if (e < NE) {
            int4 s4 = *(const int4*)(src + e);
            int4 d4 = *(const int4*)(dst + e);
            int ss[4] = {s4.x, s4.y, s4.z, s4.w};
            int dd[4] = {d4.x, d4.y, d4.z, d4.w};
#pragma unroll
            for (int q = 0; q < 4; ++q) {
                int k = dd[q] >> 8;
                int p = (incl[k] - cnt[k]) + atomicAdd(&lfill[k], 1);
                buf[p] = {ss[q], dd[q]};
            }
        }
    }
    __syncthreads();
    // phase D: coalesced run writes
    int n = min(4096, NE - blockIdx.x * 4096);
    for (int i = t; i < n; i += 256) {
        int2 pr = buf[i];
        int k = pr.y >> 8;
        pairs[rung[k] + (i - (incl[k] - cnt[k]))] = pr;
    }
}

__global__ __launch_bounds__(256) void build_csr(
    const int2* __restrict__ pairs, const int* __restrict__ bbase,
    int* __restrict__ rowptr, float* __restrict__ invcnt,
    int* __restrict__ csr_src) {
    __shared__ int cnt[256];
    __shared__ int incl[256];
    __shared__ int lfill[256];
    __shared__ int sbuf[BCAP];
    int b = blockIdx.x, t = threadIdx.x;
    int pbeg = bbase[b], pend = bbase[b + 1];
    int sz = pend - pbeg;
    cnt[t] = 0;
    lfill[t] = 0;
    __syncthreads();
    for (int i = t; i < sz; i += 256)
        atomicAdd(&cnt[pairs[pbeg + i].y & 255], 1);
    __syncthreads();
    incl[t] = cnt[t];
    __syncthreads();
    LDS_SCAN256(incl, t);
    int node = b * 256 + t;
    int c = cnt[t];
    if (node < NN) {
        rowptr[node] = pbeg + incl[t] - c;   // global exclusive position
        invcnt[node] = 1.0f / (float)(c > 0 ? c : 1);
    }
    if (sz <= BCAP) {
        for (int i = t; i < sz; i += 256) {
            int2 pr = pairs[pbeg + i];
            int ld = pr.y & 255;
            sbuf[(incl[ld] - cnt[ld]) + atomicAdd(&lfill[ld], 1)] = pr.x;
        }
        __syncthreads();
        for (int i = t; i < sz; i += 256) csr_src[pbeg + i] = sbuf[i];
    } else {  // safety fallback (not hit for uniform dst)
        for (int i = t; i < sz; i += 256) {
            int2 pr = pairs[pbeg + i];
            int ld = pr.y & 255;
            csr_src[pbeg + (incl[ld] - cnt[ld]) + atomicAdd(&lfill[ld], 1)] = pr.x;
        }
    }
}

// ---------------- prep: pack weights into MFMA B-fragment order (bf16) ----------------

__device__ __forceinline__ void pack_one(const float* Wl, const float* Wr, int D,
                                         unsigned short* Wpk, int i) {
    int j = i & 7;
    int lane = (i >> 3) & 63;
    int ct = (i >> 9) & 7;
    int ks = i >> 12;
    int k = ks * 32 + ((lane >> 4) << 3) + j;
    int c = ct * 16 + (lane & 15);
    float v = (k < D) ? Wl[c * D + k] : Wr[c * D + (k - D)];
    Wpk[i] = f2bf(v);
}

__global__ void pack_weights(const float* __restrict__ Wl0, const float* __restrict__ Wr0,
                             const float* __restrict__ Wl1, const float* __restrict__ Wr1,
                             const float* __restrict__ Wl2, const float* __restrict__ Wr2,
                             unsigned short* __restrict__ Wpk0,
                             unsigned short* __restrict__ Wpk1,
                             unsigned short* __restrict__ Wpk2) {
    const int S0 = 2 * DIN * HD;   // 16384
    const int S12 = 2 * HD * HD;   // 32768
    int i = blockIdx.x * blockDim.x + threadIdx.x;
    if (i < S0) { pack_one(Wl0, Wr0, DIN, Wpk0, i); return; }
    int j = i - S0;
    if (j < S12) { pack_one(Wl1, Wr1, HD, Wpk1, j); return; }
    int m = j - S12;
    if (m < S12) pack_one(Wl2, Wr2, HD, Wpk2, m);
}

// ---------------- gather-mean layer 0 (+fused x->bf16 conversion) ----------------
// block n: groups g=0..7 (16 threads each) gather-mean x rows into A0[n][0:64];
// additionally g==1 converts x[n] itself into A0[n][64:128].

__global__ void gather_mean_x(const float* __restrict__ x, const int* __restrict__ rowptr,
                              const int* __restrict__ csr_src, const float* __restrict__ invcnt,
                              unsigned short* __restrict__ A0) {
    __shared__ float4 red[128];
    int n = blockIdx.x, t = threadIdx.x;
    int c4 = t & 15;
    int g = t >> 4;
    int beg = rowptr[n], end = rowptr[n + 1];
    float4 acc = {0.f, 0.f, 0.f, 0.f};
    for (int e = beg + g; e < end; e += 8) {
        float4 v = ((const float4*)(x + (size_t)csr_src[e] * DIN))[c4];
        acc.x += v.x; acc.y += v.y; acc.z += v.z; acc.w += v.w;
    }
    red[t] = acc;
    // fused conv_x: g==1 converts this node's own x row (16 float4 chunks)
    if (g == 1) {
        float4 v = ((const float4*)(x + (size_t)n * DIN))[c4];
        us4 o = {f2bf(v.x), f2bf(v.y), f2bf(v.z), f2bf(v.w)};
        *(us4*)(A0 + (size_t)n * 128 + 64 + c4 * 4) = o;
    }
    __syncthreads();
    if (g == 0) {
#pragma unroll
        for (int j = 1; j < 8; ++j) {
            float4 v = red[j * 16 + c4];
            acc.x += v.x; acc.y += v.y; acc.z += v.z; acc.w += v.w;
        }
        float ic = invcnt[n];
        us4 o = {f2bf(acc.x * ic), f2bf(acc.y * ic), f2bf(acc.z * ic), f2bf(acc.w * ic)};
        *(us4*)(A0 + (size_t)n * 128 + c4 * 4) = o;
    }
}

// ---------------- gather-mean layers 1,2: bf16 h in (A12[:,128:256]), bf16 mean out ----------------

__global__ void gather_mean_h(const unsigned short* __restrict__ A12,
                              const int* __restrict__ rowptr, const int* __restrict__ csr_src,
                              const float* __restrict__ invcnt, unsigned short* __restrict__ Am) {
    __shared__ float red[128 * 8];
    int n = blockIdx.x, t = threadIdx.x;
    int c8 = t & 15;
    int g = t >> 4;
    int beg = rowptr[n], end = rowptr[n + 1];
    float acc[8] = {};
    const unsigned short* hbase = A12 + 128 + (size_t)c8 * 8;
    for (int e = beg + g; e < end; e += 8) {
        us8 v = *(const us8*)(hbase + (size_t)csr_src[e] * 256);
#pragma unroll
        for (int j = 0; j < 8; ++j) acc[j] += bf2f(v[j]);
    }
#pragma unroll
    for (int j = 0; j < 8; ++j) red[t * 8 + j] = acc[j];
    __syncthreads();
    if (g == 0) {
#pragma unroll
        for (int grp = 1; grp < 8; ++grp)
#pragma unroll
            for (int j = 0; j < 8; ++j) acc[j] += red[(grp * 16 + c8) * 8 + j];
        float ic = invcnt[n];
        us8 o;
#pragma unroll
        for (int j = 0; j < 8; ++j) o[j] = f2bf(acc[j] * ic);
        *(us8*)(Am + (size_t)n * 256 + c8 * 8) = o;
    }
}

// ---------------- fused MFMA GEMM + bias + L2 norm + (ReLU) ----------------

template <int K, bool RELU, bool F32OUT, bool BF16H>
__global__ __launch_bounds__(256) void linear_mfma(
    const unsigned short* __restrict__ A, const unsigned short* __restrict__ Wpk,
    const float* __restrict__ bias, float* __restrict__ outF,
    unsigned short* __restrict__ Hn /* h-part base (stride 256) */) {
    constexpr int NK = K / 32;
    __shared__ float rsum[2][32];
    int tid = threadIdx.x;
    int lane = tid & 63, w = tid >> 6;
    int rg = w >> 1, cg = w & 1;
    int r0 = blockIdx.x * 32 + rg * 16;
    int row_l = lane & 15, kb = lane >> 4;

    const unsigned short* Arow = A + (size_t)(r0 + row_l) * K + kb * 8;
    const unsigned short* Wp = Wpk + ((size_t)(cg * 4) * 64 + lane) * 8;

    f32x4 acc[4] = {{0.f, 0.f, 0.f, 0.f}, {0.f, 0.f, 0.f, 0.f},
                    {0.f, 0.f, 0.f, 0.f}, {0.f, 0.f, 0.f, 0.f}};
#pragma unroll
    for (int ks = 0; ks < NK; ++ks) {
        short8 a = *(const short8*)(Arow + ks * 32);
#pragma unroll
        for (int t = 0; t < 4; ++t) {
            short8 b = *(const short8*)(Wp + ((size_t)ks * 8 + t) * 64 * 8);
            acc[t] = __builtin_amdgcn_mfma_f32_16x16x32_bf16(a, b, acc[t], 0, 0, 0);
        }
    }

    float sq[4] = {0.f, 0.f, 0.f, 0.f};
#pragma unroll
    for (int t = 0; t < 4; ++t) {
        float bv = bias[cg * 64 + t * 16 + row_l];
#pragma unroll
        for (int r = 0; r < 4; ++r) {
            acc[t][r] += bv;
            sq[r] = fmaf(acc[t][r], acc[t][r], sq[r]);
        }
    }
#pragma unroll
    for (int off = 1; off < 16; off <<= 1)
#pragma unroll
        for (int r = 0; r < 4; ++r) sq[r] += __shfl_xor(sq[r], off, 64);

    if (row_l == 0) {
#pragma unroll
        for (int r = 0; r < 4; ++r) rsum[cg][rg * 16 + kb * 4 + r] = sq[r];
    }
    __syncthreads();  // also orders all A reads before the BF16H in-place writes

    int rbase = rg * 16 + kb * 4;
#pragma unroll
    for (int r = 0; r < 4; ++r) {
        int row = r0 + kb * 4 + r;
        if (row >= NN) continue;
        float n2 = rsum[0][rbase + r] + rsum[1][rbase + r];
        float inv = 1.0f / fmaxf(sqrtf(n2), 1e-12f);
#pragma unroll
        for (int t = 0; t < 4; ++t) {
            float v = acc[t][r] * inv;
            if (RELU) v = fmaxf(v, 0.f);
            int c = cg * 64 + t * 16 + row_l;
            if (F32OUT) outF[(size_t)row * HD + c] = v;
            if (BF16H) Hn[(size_t)row * 256 + c] = f2bf(v);
        }
    }
}

// ---------------- launch ----------------

static inline size_t align256(size_t x) { return (x + 255) & ~(size_t)255; }

extern "C" void kernel_launch(void* const* d_in, const int* in_sizes, int n_in,
                              void* d_out, int out_size, void* d_ws, size_t ws_size,
                              hipStream_t stream) {
    const float* x   = (const float*)d_in[0];
    const int*   ei  = (const int*)d_in[1];
    const float* Wl0 = (const float*)d_in[2];
    const float* bl0 = (const float*)d_in[3];
    const float* Wr0 = (const float*)d_in[4];
    const float* Wl1 = (const float*)d_in[5];
    const float* bl1 = (const float*)d_in[6];
    const float* Wr1 = (const float*)d_in[7];
    const float* Wl2 = (const float*)d_in[8];
    const float* bl2 = (const float*)d_in[9];
    const float* Wr2 = (const float*)d_in[10];

    const int* src = ei;
    const int* dst = ei + NE;

    // workspace carve-up
    char* p = (char*)d_ws;
    size_t off = 0;
    int* meta = (int*)(p + off);            off = align256(off + 512 * 4);  // bcnt[256]+bfill[256]
    int* bbase = (int*)(p + off);           off = align256(off + 256 * 4);
    int* rowptr = (int*)(p + off);          off = align256(off + (size_t)(NN + 1) * 4);
    int* csr_src = (int*)(p + off);         off = align256(off + (size_t)NE * 4);
    float* invcnt = (float*)(p + off);      off = align256(off + (size_t)NN * 4);
    unsigned short* A0 = (unsigned short*)(p + off);   off = align256(off + (size_t)NNP * 128 * 2);
    unsigned short* A12 = (unsigned short*)(p + off);  off = align256(off + (size_t)NNP * 256 * 2);
    unsigned short* Wpk0 = (unsigned short*)(p + off); off = align256(off + (size_t)2 * DIN * HD * 2);
    unsigned short* Wpk1 = (unsigned short*)(p + off); off = align256(off + (size_t)2 * HD * HD * 2);
    unsigned short* Wpk2 = (unsigned short*)(p + off); off = align256(off + (size_t)2 * HD * HD * 2);
    (void)ws_size; (void)n_in; (void)in_sizes; (void)out_size;

    int* bcnt = meta;
    int* bfill = meta + 256;
    int2* pairs = (int2*)A0;  // 6.4MB alias inside A0's 12.8MB; consumed before A0 writes

    float* out = (float*)d_out;

    // CSR build: two-level LDS counting sort (coalesced writes, no cross-XCD line sharing)
    zero_meta<<<1, 512, 0, stream>>>(meta);
    bucket_count<<<SB, 256, 0, stream>>>(dst, bcnt);
    bucket_scan<<<1, 256, 0, stream>>>(bcnt, bbase, rowptr);
    bucket_scatter<<<SB, 256, 0, stream>>>(src, dst, bbase, bfill, pairs);
    build_csr<<<NBUK, 256, 0, stream>>>(pairs, bbase, rowptr, invcnt, csr_src);

    // prep: packed weights (independent of CSR)
    const int WTOT = 2 * DIN * HD + 2 * 2 * HD * HD;  // 81920
    pack_weights<<<(WTOT + 255) / 256, 256, 0, stream>>>(Wl0, Wr0, Wl1, Wr1, Wl2, Wr2,
                                                         Wpk0, Wpk1, Wpk2);

    const int LG = NNP / 32;  // 1563

    // layer 0: gather x (+fused x->bf16) -> A0; GEMM K=128 -> h0 bf16 into A12[:,128:256]
    gather_mean_x<<<NN, 128, 0, stream>>>(x, rowptr, csr_src, invcnt, A0);
    linear_mfma<2 * DIN, true, false, true><<<LG, 256, 0, stream>>>(
        A0, Wpk0, bl0, nullptr, A12 + 128);

    // layer 1: gather h0 (bf16) -> A12 mean part; GEMM K=256 -> h1 bf16 (in place)
    gather_mean_h<<<NN, 128, 0, stream>>>(A12, rowptr, csr_src, invcnt, A12);
    linear_mfma<2 * HD, true, false, true><<<LG, 256, 0, stream>>>(
        A12, Wpk1, bl1, nullptr, A12 + 128);

    // layer 2: gather h1 -> A12 mean part; GEMM K=256 -> f32 d_out
    gather_mean_h<<<NN, 128, 0, stream>>>(A12, rowptr, csr_src, invcnt, A12);
    linear_mfma<2 * HD, false, true, false><<<LG, 256, 0, stream>>>(
        A12, Wpk2, bl2, out, nullptr);
}